// Round 2
// baseline (1496.010 us; speedup 1.0000x reference)
//
#include <hip/hip_runtime.h>
#include <hip/hip_bf16.h>
#include <math.h>

#define Nn 50000
#define Ee 800000
#define Cc 16
#define Mm 32
#define Gg 8

// ---------------------------------------------------------------------------
// dtype-agnostic load/store helpers. isbf is wave-uniform -> scalar branch.
// ---------------------------------------------------------------------------
__device__ __forceinline__ float ldin(const void* p, int idx, int isbf) {
    if (isbf) return __bfloat162float(((const __hip_bfloat16*)p)[idx]);
    return ((const float*)p)[idx];
}
__device__ __forceinline__ void stout(void* p, size_t idx, float v, int isbf) {
    if (isbf) ((__hip_bfloat16*)p)[idx] = __float2bfloat16(v);
    else ((float*)p)[idx] = v;
}

// ---------------------------------------------------------------------------
// Kernel 1: dtype detection + softmax tables (single block)
//   Detection: if B0 is bf16, low uint16 of each 32b word is a bf16 in
//   [-5,5] -> exponent field in [123,129]. If fp32, low uint16 is mantissa
//   noise -> ~4% hit rate. Count over 64 words.
// ---------------------------------------------------------------------------
__global__ void detect_and_tables(const void* __restrict__ B0,
                                  const void* __restrict__ Pi,
                                  const void* __restrict__ B1,
                                  const void* __restrict__ Q,
                                  int* __restrict__ flag_ws,
                                  float* __restrict__ smB0,
                                  float* __restrict__ smPi,
                                  float* __restrict__ smB1,
                                  float* __restrict__ smQ) {
    __shared__ int sflag;
    if (threadIdx.x == 0) {
        const unsigned int* w = (const unsigned int*)B0;
        int cnt = 0;
        for (int k = 0; k < 64; ++k) {
            unsigned int ex = (w[k] >> 7) & 0xFFu;   // low-half "exponent" field
            if (ex >= 120u && ex <= 130u) cnt++;
        }
        sflag = (cnt >= 48) ? 1 : 0;
        *flag_ws = sflag;
    }
    __syncthreads();
    const int isbf = sflag;
    int tid = threadIdx.x;

    // B0 / B1: col = c*G + g, softmax over m (stride G)
    if (tid < 128) {
        int c = tid / Gg, g = tid % Gg;
        int base = c * (Mm * Gg) + g;
        float mx = -1e30f;
        for (int m = 0; m < Mm; ++m) mx = fmaxf(mx, ldin(B0, base + m * Gg, isbf));
        float s = 0.f;
        for (int m = 0; m < Mm; ++m) s += __expf(ldin(B0, base + m * Gg, isbf) - mx);
        float inv = 1.0f / s;
        for (int m = 0; m < Mm; ++m)
            smB0[base + m * Gg] = __expf(ldin(B0, base + m * Gg, isbf) - mx) * inv;
    } else if (tid < 256) {
        int t = tid - 128;
        int c = t / Gg, g = t % Gg;
        int base = c * (Mm * Gg) + g;
        float mx = -1e30f;
        for (int m = 0; m < Mm; ++m) mx = fmaxf(mx, ldin(B1, base + m * Gg, isbf));
        float s = 0.f;
        for (int m = 0; m < Mm; ++m) s += __expf(ldin(B1, base + m * Gg, isbf) - mx);
        float inv = 1.0f / s;
        for (int m = 0; m < Mm; ++m)
            smB1[base + m * Gg] = __expf(ldin(B1, base + m * Gg, isbf) - mx) * inv;
    }

    // Q[i,l,g]: softmax over i (stride C*G)
    if (tid < 128) {
        int l = tid / Gg, g = tid % Gg;
        int base = l * Gg + g;
        float mx = -1e30f;
        for (int i = 0; i < Cc; ++i) mx = fmaxf(mx, ldin(Q, base + i * Cc * Gg, isbf));
        float s = 0.f;
        for (int i = 0; i < Cc; ++i) s += __expf(ldin(Q, base + i * Cc * Gg, isbf) - mx);
        float inv = 1.0f / s;
        for (int i = 0; i < Cc; ++i)
            smQ[base + i * Cc * Gg] = __expf(ldin(Q, base + i * Cc * Gg, isbf) - mx) * inv;
    }

    // Pi[c,g]: softmax over c (stride G)
    if (tid < Gg) {
        int g = tid;
        float mx = -1e30f;
        for (int c = 0; c < Cc; ++c) mx = fmaxf(mx, ldin(Pi, c * Gg + g, isbf));
        float s = 0.f;
        for (int c = 0; c < Cc; ++c) s += __expf(ldin(Pi, c * Gg + g, isbf) - mx);
        float inv = 1.0f / s;
        for (int c = 0; c < Cc; ++c)
            smPi[c * Gg + g] = __expf(ldin(Pi, c * Gg + g, isbf) - mx) * inv;
    }
}

// ---------------------------------------------------------------------------
// Kernel 2: layer 0 — one thread per (n, g)
// ---------------------------------------------------------------------------
__global__ void layer0_kernel(const int* __restrict__ x,
                              const float* __restrict__ smPi,
                              const float* __restrict__ smB0,
                              const int* __restrict__ flag_ws,
                              float* __restrict__ post0,
                              void* __restrict__ out) {
    int tid = blockIdx.x * blockDim.x + threadIdx.x;
    if (tid >= Nn * Gg) return;
    const int isbf = *flag_ws;
    int n = tid / Gg, g = tid % Gg;
    int xv = x[n];
    float u[Cc];
    float norm = 0.f;
#pragma unroll
    for (int c = 0; c < Cc; ++c) {
        float v = smPi[c * Gg + g] * smB0[(c * Mm + xv) * Gg + g];
        u[c] = v;
        norm += v;
    }
    float inv = 1.0f / norm;
#pragma unroll
    for (int c = 0; c < Cc; ++c) post0[n * (Cc * Gg) + c * Gg + g] = u[c] * inv;
    stout(out, (size_t)n * (2 * Gg) + g, logf(norm), isbf);
}

// ---------------------------------------------------------------------------
// Kernel 3: edge scatter — 32 threads per edge, float4 gather + 4 fp32 atomics
// ---------------------------------------------------------------------------
__global__ void edge_scatter(const int* __restrict__ ei,
                             const float* __restrict__ post0,
                             float* __restrict__ aggr,
                             float* __restrict__ cnt) {
    long long tid = (long long)blockIdx.x * blockDim.x + threadIdx.x;
    if (tid >= (long long)Ee * 32) return;
    int e = (int)(tid >> 5);
    int j = (int)(tid & 31);
    int s = ei[e];            // src (segment id)
    int d = ei[Ee + e];       // dst (gather id)
    const float4 v = *(const float4*)(post0 + (size_t)d * 128 + j * 4);
    float* a = aggr + (size_t)s * 128 + j * 4;
    atomicAdd(a + 0, v.x);
    atomicAdd(a + 1, v.y);
    atomicAdd(a + 2, v.z);
    atomicAdd(a + 3, v.w);
    if (j == 0) atomicAdd(cnt + s, 1.0f);
}

// ---------------------------------------------------------------------------
// Kernel 4: layer 1 — one thread per (n, g); smQ staged in LDS (8 KB)
// ---------------------------------------------------------------------------
__global__ void layer1_kernel(const int* __restrict__ x,
                              const float* __restrict__ smB1,
                              const float* __restrict__ smQ,
                              const float* __restrict__ aggr,
                              const float* __restrict__ cnt,
                              const int* __restrict__ flag_ws,
                              void* __restrict__ out) {
    __shared__ float sQ[Cc * Cc * Gg];
    for (int i = threadIdx.x; i < Cc * Cc * Gg; i += blockDim.x) sQ[i] = smQ[i];
    __syncthreads();

    int tid = blockIdx.x * blockDim.x + threadIdx.x;
    if (tid >= Nn * Gg) return;
    const int isbf = *flag_ws;
    int n = tid / Gg, g = tid % Gg;

    float inv_cnt = 1.0f / fmaxf(cnt[n], 1.0f);
    float al[Cc];
#pragma unroll
    for (int l = 0; l < Cc; ++l) al[l] = aggr[(size_t)n * 128 + l * Gg + g] * inv_cnt;

    int xv = x[n];
    float t[Cc];
    float norm = 0.f;
#pragma unroll
    for (int i = 0; i < Cc; ++i) {
        float qa = 0.f;
#pragma unroll
        for (int l = 0; l < Cc; ++l) qa += sQ[(i * Cc + l) * Gg + g] * al[l];
        float v = smB1[(i * Mm + xv) * Gg + g] * qa;
        t[i] = v;
        norm += v;
    }
    float inv = 1.0f / norm;
#pragma unroll
    for (int i = 0; i < Cc; ++i)
        stout(out, (size_t)Nn * 2 * Gg + (size_t)n * (Cc * Gg) + i * Gg + g, t[i] * inv, isbf);
    stout(out, (size_t)n * (2 * Gg) + Gg + g, logf(norm), isbf);
}

// ---------------------------------------------------------------------------
extern "C" void kernel_launch(void* const* d_in, const int* in_sizes, int n_in,
                              void* d_out, int out_size, void* d_ws, size_t ws_size,
                              hipStream_t stream) {
    const int* x  = (const int*)d_in[0];
    const int* ei = (const int*)d_in[1];
    const void* B0 = d_in[2];
    const void* Pi = d_in[3];
    const void* B1 = d_in[4];
    const void* Q  = d_in[5];

    // Workspace layout (fp32 words): flag + tables + post0 + aggr + cnt
    float* ws    = (float*)d_ws;
    int*   flag  = (int*)ws;                // 1 word (padded to 128)
    float* smPi  = ws + 128;                // 128
    float* smB0  = smPi + 128;              // 4096
    float* smB1  = smB0 + 4096;             // 4096
    float* smQ   = smB1 + 4096;             // 2048
    float* post0 = smQ + 2048;              // N*C*G = 6,400,000
    float* aggr  = post0 + (size_t)Nn * Cc * Gg;   // 6,400,000
    float* cnt   = aggr + (size_t)Nn * Cc * Gg;    // 50,000

    // zero aggr + cnt (contiguous)
    hipMemsetAsync(aggr, 0, ((size_t)Nn * Cc * Gg + Nn) * sizeof(float), stream);

    detect_and_tables<<<1, 256, 0, stream>>>(B0, Pi, B1, Q, flag, smB0, smPi, smB1, smQ);

    int ng = Nn * Gg;  // 400,000
    layer0_kernel<<<(ng + 255) / 256, 256, 0, stream>>>(x, smPi, smB0, flag, post0, d_out);

    long long et = (long long)Ee * 32;  // 25.6M threads
    edge_scatter<<<(int)((et + 255) / 256), 256, 0, stream>>>(ei, post0, aggr, cnt);

    layer1_kernel<<<(ng + 255) / 256, 256, 0, stream>>>(x, smB1, smQ, aggr, cnt, flag, d_out);
}

// Round 3
// 373.893 us; speedup vs baseline: 4.0012x; 4.0012x over previous
//
#include <hip/hip_runtime.h>
#include <hip/hip_bf16.h>
#include <math.h>

#define Nn 50000
#define Ee 800000
#define Cc 16
#define Mm 32
#define Gg 8

// ---------------------------------------------------------------------------
// dtype-agnostic load/store helpers. isbf is wave-uniform -> scalar branch.
// ---------------------------------------------------------------------------
__device__ __forceinline__ float ldin(const void* p, int idx, int isbf) {
    if (isbf) return __bfloat162float(((const __hip_bfloat16*)p)[idx]);
    return ((const float*)p)[idx];
}
__device__ __forceinline__ void stout(void* p, size_t idx, float v, int isbf) {
    if (isbf) ((__hip_bfloat16*)p)[idx] = __float2bfloat16(v);
    else ((float*)p)[idx] = v;
}

// ---------------------------------------------------------------------------
// Kernel 1: dtype detection + softmax tables (single block)
// ---------------------------------------------------------------------------
__global__ void detect_and_tables(const void* __restrict__ B0,
                                  const void* __restrict__ Pi,
                                  const void* __restrict__ B1,
                                  const void* __restrict__ Q,
                                  int* __restrict__ flag_ws,
                                  float* __restrict__ smB0,
                                  float* __restrict__ smPi,
                                  float* __restrict__ smB1,
                                  float* __restrict__ smQ) {
    __shared__ int sflag;
    if (threadIdx.x == 0) {
        const unsigned int* w = (const unsigned int*)B0;
        int cnt = 0;
        for (int k = 0; k < 64; ++k) {
            unsigned int ex = (w[k] >> 7) & 0xFFu;   // low-half "exponent" field
            if (ex >= 120u && ex <= 130u) cnt++;
        }
        sflag = (cnt >= 48) ? 1 : 0;
        *flag_ws = sflag;
    }
    __syncthreads();
    const int isbf = sflag;
    int tid = threadIdx.x;

    // B0 / B1: col = c*G + g, softmax over m (stride G)
    if (tid < 128) {
        int c = tid / Gg, g = tid % Gg;
        int base = c * (Mm * Gg) + g;
        float mx = -1e30f;
        for (int m = 0; m < Mm; ++m) mx = fmaxf(mx, ldin(B0, base + m * Gg, isbf));
        float s = 0.f;
        for (int m = 0; m < Mm; ++m) s += __expf(ldin(B0, base + m * Gg, isbf) - mx);
        float inv = 1.0f / s;
        for (int m = 0; m < Mm; ++m)
            smB0[base + m * Gg] = __expf(ldin(B0, base + m * Gg, isbf) - mx) * inv;
    } else if (tid < 256) {
        int t = tid - 128;
        int c = t / Gg, g = t % Gg;
        int base = c * (Mm * Gg) + g;
        float mx = -1e30f;
        for (int m = 0; m < Mm; ++m) mx = fmaxf(mx, ldin(B1, base + m * Gg, isbf));
        float s = 0.f;
        for (int m = 0; m < Mm; ++m) s += __expf(ldin(B1, base + m * Gg, isbf) - mx);
        float inv = 1.0f / s;
        for (int m = 0; m < Mm; ++m)
            smB1[base + m * Gg] = __expf(ldin(B1, base + m * Gg, isbf) - mx) * inv;
    }

    // Q[i,l,g]: softmax over i (stride C*G)
    if (tid < 128) {
        int l = tid / Gg, g = tid % Gg;
        int base = l * Gg + g;
        float mx = -1e30f;
        for (int i = 0; i < Cc; ++i) mx = fmaxf(mx, ldin(Q, base + i * Cc * Gg, isbf));
        float s = 0.f;
        for (int i = 0; i < Cc; ++i) s += __expf(ldin(Q, base + i * Cc * Gg, isbf) - mx);
        float inv = 1.0f / s;
        for (int i = 0; i < Cc; ++i)
            smQ[base + i * Cc * Gg] = __expf(ldin(Q, base + i * Cc * Gg, isbf) - mx) * inv;
    }

    // Pi[c,g]: softmax over c (stride G)
    if (tid < Gg) {
        int g = tid;
        float mx = -1e30f;
        for (int c = 0; c < Cc; ++c) mx = fmaxf(mx, ldin(Pi, c * Gg + g, isbf));
        float s = 0.f;
        for (int c = 0; c < Cc; ++c) s += __expf(ldin(Pi, c * Gg + g, isbf) - mx);
        float inv = 1.0f / s;
        for (int c = 0; c < Cc; ++c)
            smPi[c * Gg + g] = __expf(ldin(Pi, c * Gg + g, isbf) - mx) * inv;
    }
}

// ---------------------------------------------------------------------------
// Kernel 2: layer 0 — one thread per (n, g)
// ---------------------------------------------------------------------------
__global__ void layer0_kernel(const int* __restrict__ x,
                              const float* __restrict__ smPi,
                              const float* __restrict__ smB0,
                              const int* __restrict__ flag_ws,
                              float* __restrict__ post0,
                              void* __restrict__ out) {
    int tid = blockIdx.x * blockDim.x + threadIdx.x;
    if (tid >= Nn * Gg) return;
    const int isbf = *flag_ws;
    int n = tid / Gg, g = tid % Gg;
    int xv = x[n];
    float u[Cc];
    float norm = 0.f;
#pragma unroll
    for (int c = 0; c < Cc; ++c) {
        float v = smPi[c * Gg + g] * smB0[(c * Mm + xv) * Gg + g];
        u[c] = v;
        norm += v;
    }
    float inv = 1.0f / norm;
#pragma unroll
    for (int c = 0; c < Cc; ++c) post0[n * (Cc * Gg) + c * Gg + g] = u[c] * inv;
    stout(out, (size_t)n * (2 * Gg) + g, logf(norm), isbf);
}

// ---------------------------------------------------------------------------
// CSR build: count -> scan -> fill
// ---------------------------------------------------------------------------
__global__ void count_kernel(const int* __restrict__ ei, int* __restrict__ deg) {
    int e = blockIdx.x * blockDim.x + threadIdx.x;
    if (e >= Ee) return;
    atomicAdd(&deg[ei[e]], 1);
}

__global__ void scan_kernel(const int* __restrict__ deg,
                            int* __restrict__ offs,
                            int* __restrict__ cursor) {
    __shared__ int part[1024];
    int t = threadIdx.x;
    const int CH = (Nn + 1023) / 1024;   // 49
    int lo = t * CH;
    int hi = lo + CH; if (hi > Nn) hi = Nn;
    int s = 0;
    for (int i = lo; i < hi; ++i) s += deg[i];
    part[t] = s;
    __syncthreads();
    // Hillis-Steele inclusive scan over 1024 partials
    for (int off = 1; off < 1024; off <<= 1) {
        int v = (t >= off) ? part[t - off] : 0;
        __syncthreads();
        part[t] += v;
        __syncthreads();
    }
    int run = (t == 0) ? 0 : part[t - 1];   // exclusive prefix of this chunk
    for (int i = lo; i < hi; ++i) {
        offs[i] = run;
        cursor[i] = run;
        run += deg[i];
    }
}

__global__ void fill_kernel(const int* __restrict__ ei,
                            int* __restrict__ cursor,
                            int* __restrict__ sorted_dst) {
    int e = blockIdx.x * blockDim.x + threadIdx.x;
    if (e >= Ee) return;
    int s = ei[e], d = ei[Ee + e];
    int pos = atomicAdd(&cursor[s], 1);
    sorted_dst[pos] = d;
}

// ---------------------------------------------------------------------------
// Kernel 3: aggregation — one wave (64 lanes) per node, NO atomics.
//   halves process 2 edges/iter; lane j of a half reads float4 j of
//   post0[dst] (32 lanes x 16B = fully-coalesced 512B row). Mean applied here.
// ---------------------------------------------------------------------------
__global__ void aggr_kernel(const int* __restrict__ offs,
                            const int* __restrict__ deg,
                            const int* __restrict__ sorted_dst,
                            const float* __restrict__ post0,
                            float* __restrict__ aggr) {
    int wave = (int)((blockIdx.x * (long long)blockDim.x + threadIdx.x) >> 6);
    if (wave >= Nn) return;
    int lane = threadIdx.x & 63;
    int h = lane >> 5, j = lane & 31;
    int start = offs[wave];
    int d = deg[wave];
    int end = start + d;
    float4 acc = {0.f, 0.f, 0.f, 0.f};
    for (int e = start + h; e < end; e += 2) {
        int dst = sorted_dst[e];
        const float4 v = *(const float4*)(post0 + (size_t)dst * 128 + j * 4);
        acc.x += v.x; acc.y += v.y; acc.z += v.z; acc.w += v.w;
    }
    // combine the two halves
    acc.x += __shfl_xor(acc.x, 32, 64);
    acc.y += __shfl_xor(acc.y, 32, 64);
    acc.z += __shfl_xor(acc.z, 32, 64);
    acc.w += __shfl_xor(acc.w, 32, 64);
    if (h == 0) {
        float inv = 1.0f / fmaxf((float)d, 1.0f);
        float4 r = {acc.x * inv, acc.y * inv, acc.z * inv, acc.w * inv};
        *(float4*)(aggr + (size_t)wave * 128 + j * 4) = r;
    }
}

// ---------------------------------------------------------------------------
// Kernel 4: layer 1 — one thread per (n, g); smQ staged in LDS (8 KB)
// ---------------------------------------------------------------------------
__global__ void layer1_kernel(const int* __restrict__ x,
                              const float* __restrict__ smB1,
                              const float* __restrict__ smQ,
                              const float* __restrict__ aggr,
                              const int* __restrict__ flag_ws,
                              void* __restrict__ out) {
    __shared__ float sQ[Cc * Cc * Gg];
    for (int i = threadIdx.x; i < Cc * Cc * Gg; i += blockDim.x) sQ[i] = smQ[i];
    __syncthreads();

    int tid = blockIdx.x * blockDim.x + threadIdx.x;
    if (tid >= Nn * Gg) return;
    const int isbf = *flag_ws;
    int n = tid / Gg, g = tid % Gg;

    float al[Cc];
#pragma unroll
    for (int l = 0; l < Cc; ++l) al[l] = aggr[(size_t)n * 128 + l * Gg + g];

    int xv = x[n];
    float t[Cc];
    float norm = 0.f;
#pragma unroll
    for (int i = 0; i < Cc; ++i) {
        float qa = 0.f;
#pragma unroll
        for (int l = 0; l < Cc; ++l) qa += sQ[(i * Cc + l) * Gg + g] * al[l];
        float v = smB1[(i * Mm + xv) * Gg + g] * qa;
        t[i] = v;
        norm += v;
    }
    float inv = 1.0f / norm;
#pragma unroll
    for (int i = 0; i < Cc; ++i)
        stout(out, (size_t)Nn * 2 * Gg + (size_t)n * (Cc * Gg) + i * Gg + g, t[i] * inv, isbf);
    stout(out, (size_t)n * (2 * Gg) + Gg + g, logf(norm), isbf);
}

// ---------------------------------------------------------------------------
extern "C" void kernel_launch(void* const* d_in, const int* in_sizes, int n_in,
                              void* d_out, int out_size, void* d_ws, size_t ws_size,
                              hipStream_t stream) {
    const int* x  = (const int*)d_in[0];
    const int* ei = (const int*)d_in[1];
    const void* B0 = d_in[2];
    const void* Pi = d_in[3];
    const void* B1 = d_in[4];
    const void* Q  = d_in[5];

    // Workspace layout (fp32 words):
    float* ws    = (float*)d_ws;
    int*   flag  = (int*)ws;                       // 1 (padded to 128)
    float* smPi  = ws + 128;                       // 128
    float* smB0  = smPi + 128;                     // 4096
    float* smB1  = smB0 + 4096;                    // 4096
    float* smQ   = smB1 + 4096;                    // 2048
    float* post0 = smQ + 2048;                     // 6,400,000 (16-aligned)
    float* aggr  = post0 + (size_t)Nn * Cc * Gg;   // 6,400,000
    int*   deg        = (int*)(aggr + (size_t)Nn * Cc * Gg);  // 50,000
    int*   offs       = deg + Nn;                  // 50,000
    int*   cursor     = offs + Nn;                 // 50,000
    int*   sorted_dst = cursor + Nn;               // 800,000
    // total ~55 MB

    hipMemsetAsync(deg, 0, Nn * sizeof(int), stream);

    detect_and_tables<<<1, 256, 0, stream>>>(B0, Pi, B1, Q, flag, smB0, smPi, smB1, smQ);

    count_kernel<<<(Ee + 255) / 256, 256, 0, stream>>>(ei, deg);
    scan_kernel<<<1, 1024, 0, stream>>>(deg, offs, cursor);
    fill_kernel<<<(Ee + 255) / 256, 256, 0, stream>>>(ei, cursor, sorted_dst);

    int ng = Nn * Gg;  // 400,000
    layer0_kernel<<<(ng + 255) / 256, 256, 0, stream>>>(x, smPi, smB0, flag, post0, d_out);

    // one wave per node: Nn*64 threads
    long long at = (long long)Nn * 64;
    aggr_kernel<<<(int)((at + 255) / 256), 256, 0, stream>>>(offs, deg, sorted_dst, post0, aggr);

    layer1_kernel<<<(ng + 255) / 256, 256, 0, stream>>>(x, smB1, smQ, aggr, flag, d_out);
}

// Round 4
// 265.403 us; speedup vs baseline: 5.6368x; 1.4088x over previous
//
#include <hip/hip_runtime.h>
#include <hip/hip_bf16.h>
#include <math.h>

#define Nn 50000
#define Ee 800000
#define Cc 16
#define Mm 32
#define Gg 8

#define SCAN_T 256
#define SCAN_BLOCKS ((Nn + SCAN_T - 1) / SCAN_T)   // 196

// ---------------------------------------------------------------------------
// dtype-agnostic load/store helpers. isbf is wave-uniform -> scalar branch.
// ---------------------------------------------------------------------------
__device__ __forceinline__ float ldin(const void* p, int idx, int isbf) {
    if (isbf) return __bfloat162float(((const __hip_bfloat16*)p)[idx]);
    return ((const float*)p)[idx];
}
__device__ __forceinline__ void stout(void* p, size_t idx, float v, int isbf) {
    if (isbf) ((__hip_bfloat16*)p)[idx] = __float2bfloat16(v);
    else ((float*)p)[idx] = v;
}
__device__ __forceinline__ float bfr2f(unsigned short u) {   // raw bf16 bits -> f32
    return __uint_as_float(((unsigned int)u) << 16);
}

// ---------------------------------------------------------------------------
// Kernel 1: dtype detection + softmax tables (single block)
// ---------------------------------------------------------------------------
__global__ void detect_and_tables(const void* __restrict__ B0,
                                  const void* __restrict__ Pi,
                                  const void* __restrict__ B1,
                                  const void* __restrict__ Q,
                                  int* __restrict__ flag_ws,
                                  float* __restrict__ smB0,
                                  float* __restrict__ smPi,
                                  float* __restrict__ smB1,
                                  float* __restrict__ smQ) {
    __shared__ int sflag;
    if (threadIdx.x == 0) {
        const unsigned int* w = (const unsigned int*)B0;
        int cnt = 0;
        for (int k = 0; k < 64; ++k) {
            unsigned int ex = (w[k] >> 7) & 0xFFu;   // low-half "exponent" field
            if (ex >= 120u && ex <= 130u) cnt++;
        }
        sflag = (cnt >= 48) ? 1 : 0;
        *flag_ws = sflag;
    }
    __syncthreads();
    const int isbf = sflag;
    int tid = threadIdx.x;

    // B0 / B1: col = c*G + g, softmax over m (stride G)
    if (tid < 128) {
        int c = tid / Gg, g = tid % Gg;
        int base = c * (Mm * Gg) + g;
        float mx = -1e30f;
        for (int m = 0; m < Mm; ++m) mx = fmaxf(mx, ldin(B0, base + m * Gg, isbf));
        float s = 0.f;
        for (int m = 0; m < Mm; ++m) s += __expf(ldin(B0, base + m * Gg, isbf) - mx);
        float inv = 1.0f / s;
        for (int m = 0; m < Mm; ++m)
            smB0[base + m * Gg] = __expf(ldin(B0, base + m * Gg, isbf) - mx) * inv;
    } else if (tid < 256) {
        int t = tid - 128;
        int c = t / Gg, g = t % Gg;
        int base = c * (Mm * Gg) + g;
        float mx = -1e30f;
        for (int m = 0; m < Mm; ++m) mx = fmaxf(mx, ldin(B1, base + m * Gg, isbf));
        float s = 0.f;
        for (int m = 0; m < Mm; ++m) s += __expf(ldin(B1, base + m * Gg, isbf) - mx);
        float inv = 1.0f / s;
        for (int m = 0; m < Mm; ++m)
            smB1[base + m * Gg] = __expf(ldin(B1, base + m * Gg, isbf) - mx) * inv;
    }

    // Q[i,l,g]: softmax over i (stride C*G)
    if (tid < 128) {
        int l = tid / Gg, g = tid % Gg;
        int base = l * Gg + g;
        float mx = -1e30f;
        for (int i = 0; i < Cc; ++i) mx = fmaxf(mx, ldin(Q, base + i * Cc * Gg, isbf));
        float s = 0.f;
        for (int i = 0; i < Cc; ++i) s += __expf(ldin(Q, base + i * Cc * Gg, isbf) - mx);
        float inv = 1.0f / s;
        for (int i = 0; i < Cc; ++i)
            smQ[base + i * Cc * Gg] = __expf(ldin(Q, base + i * Cc * Gg, isbf) - mx) * inv;
    }

    // Pi[c,g]: softmax over c (stride G)
    if (tid < Gg) {
        int g = tid;
        float mx = -1e30f;
        for (int c = 0; c < Cc; ++c) mx = fmaxf(mx, ldin(Pi, c * Gg + g, isbf));
        float s = 0.f;
        for (int c = 0; c < Cc; ++c) s += __expf(ldin(Pi, c * Gg + g, isbf) - mx);
        float inv = 1.0f / s;
        for (int c = 0; c < Cc; ++c)
            smPi[c * Gg + g] = __expf(ldin(Pi, c * Gg + g, isbf) - mx) * inv;
    }
}

// ---------------------------------------------------------------------------
// Kernel 2: layer 0 — one thread per (n, g); post0 stored bf16 (gather-only)
// ---------------------------------------------------------------------------
__global__ void layer0_kernel(const int* __restrict__ x,
                              const float* __restrict__ smPi,
                              const float* __restrict__ smB0,
                              const int* __restrict__ flag_ws,
                              __hip_bfloat16* __restrict__ post0,
                              void* __restrict__ out) {
    int tid = blockIdx.x * blockDim.x + threadIdx.x;
    if (tid >= Nn * Gg) return;
    const int isbf = *flag_ws;
    int n = tid / Gg, g = tid % Gg;
    int xv = x[n];
    float u[Cc];
    float norm = 0.f;
#pragma unroll
    for (int c = 0; c < Cc; ++c) {
        float v = smPi[c * Gg + g] * smB0[(c * Mm + xv) * Gg + g];
        u[c] = v;
        norm += v;
    }
    float inv = 1.0f / norm;
#pragma unroll
    for (int c = 0; c < Cc; ++c)
        post0[n * (Cc * Gg) + c * Gg + g] = __float2bfloat16(u[c] * inv);
    stout(out, (size_t)n * (2 * Gg) + g, logf(norm), isbf);
}

// ---------------------------------------------------------------------------
// CSR build: count -> 3-phase multi-block scan -> fill
// ---------------------------------------------------------------------------
__global__ void count_kernel(const int* __restrict__ ei, int* __restrict__ deg) {
    int e = blockIdx.x * blockDim.x + threadIdx.x;
    if (e >= Ee) return;
    atomicAdd(&deg[ei[e]], 1);
}

__global__ void scanA(const int* __restrict__ deg, int* __restrict__ bsum) {
    __shared__ int s[SCAN_T];
    int i = blockIdx.x * SCAN_T + threadIdx.x;
    s[threadIdx.x] = (i < Nn) ? deg[i] : 0;
    __syncthreads();
    for (int off = SCAN_T / 2; off > 0; off >>= 1) {
        if (threadIdx.x < off) s[threadIdx.x] += s[threadIdx.x + off];
        __syncthreads();
    }
    if (threadIdx.x == 0) bsum[blockIdx.x] = s[0];
}

__global__ void scanB(const int* __restrict__ bsum, int* __restrict__ boff) {
    __shared__ int s[SCAN_T];
    int t = threadIdx.x;
    int v = (t < SCAN_BLOCKS) ? bsum[t] : 0;
    s[t] = v;
    __syncthreads();
    for (int off = 1; off < SCAN_T; off <<= 1) {
        int u = (t >= off) ? s[t - off] : 0;
        __syncthreads();
        s[t] += u;
        __syncthreads();
    }
    if (t < SCAN_BLOCKS) boff[t] = s[t] - v;   // exclusive
}

__global__ void scanC(const int* __restrict__ deg, const int* __restrict__ boff,
                      int* __restrict__ offs, int* __restrict__ cursor) {
    __shared__ int s[SCAN_T];
    int t = threadIdx.x;
    int i = blockIdx.x * SCAN_T + t;
    int v = (i < Nn) ? deg[i] : 0;
    s[t] = v;
    __syncthreads();
    for (int off = 1; off < SCAN_T; off <<= 1) {
        int u = (t >= off) ? s[t - off] : 0;
        __syncthreads();
        s[t] += u;
        __syncthreads();
    }
    int ex = s[t] - v + boff[blockIdx.x];
    if (i < Nn) { offs[i] = ex; cursor[i] = ex; }
}

__global__ void fill_kernel(const int* __restrict__ ei,
                            int* __restrict__ cursor,
                            int* __restrict__ sorted_dst) {
    int e = blockIdx.x * blockDim.x + threadIdx.x;
    if (e >= Ee) return;
    int s = ei[e], d = ei[Ee + e];
    int pos = atomicAdd(&cursor[s], 1);
    sorted_dst[pos] = d;
}

// ---------------------------------------------------------------------------
// Kernel 3: aggregation — one wave per node, NO atomics, bf16 gather.
//   Row = 256 B; lane j of a half reads ushort4 (4 bf16) at elem j*4.
//   Halves process alternating edges; shfl_xor(32) combine; fp32 accumulate.
// ---------------------------------------------------------------------------
__global__ void aggr_kernel(const int* __restrict__ offs,
                            const int* __restrict__ deg,
                            const int* __restrict__ sorted_dst,
                            const unsigned short* __restrict__ post0,
                            float* __restrict__ aggr) {
    int wave = (int)((blockIdx.x * (long long)blockDim.x + threadIdx.x) >> 6);
    if (wave >= Nn) return;
    int lane = threadIdx.x & 63;
    int h = lane >> 5, j = lane & 31;
    int start = offs[wave];
    int d = deg[wave];
    int end = start + d;
    float a0 = 0.f, a1 = 0.f, a2 = 0.f, a3 = 0.f;
    for (int e = start + h; e < end; e += 2) {
        int dst = sorted_dst[e];
        const ushort4 v = *(const ushort4*)(post0 + (size_t)dst * 128 + j * 4);
        a0 += bfr2f(v.x); a1 += bfr2f(v.y); a2 += bfr2f(v.z); a3 += bfr2f(v.w);
    }
    a0 += __shfl_xor(a0, 32, 64);
    a1 += __shfl_xor(a1, 32, 64);
    a2 += __shfl_xor(a2, 32, 64);
    a3 += __shfl_xor(a3, 32, 64);
    if (h == 0) {
        float inv = 1.0f / fmaxf((float)d, 1.0f);
        float4 r = {a0 * inv, a1 * inv, a2 * inv, a3 * inv};
        *(float4*)(aggr + (size_t)wave * 128 + j * 4) = r;
    }
}

// ---------------------------------------------------------------------------
// Kernel 4: layer 1 — one thread per (n, g); smQ staged in LDS (8 KB)
// ---------------------------------------------------------------------------
__global__ void layer1_kernel(const int* __restrict__ x,
                              const float* __restrict__ smB1,
                              const float* __restrict__ smQ,
                              const float* __restrict__ aggr,
                              const int* __restrict__ flag_ws,
                              void* __restrict__ out) {
    __shared__ float sQ[Cc * Cc * Gg];
    for (int i = threadIdx.x; i < Cc * Cc * Gg; i += blockDim.x) sQ[i] = smQ[i];
    __syncthreads();

    int tid = blockIdx.x * blockDim.x + threadIdx.x;
    if (tid >= Nn * Gg) return;
    const int isbf = *flag_ws;
    int n = tid / Gg, g = tid % Gg;

    float al[Cc];
#pragma unroll
    for (int l = 0; l < Cc; ++l) al[l] = aggr[(size_t)n * 128 + l * Gg + g];

    int xv = x[n];
    float t[Cc];
    float norm = 0.f;
#pragma unroll
    for (int i = 0; i < Cc; ++i) {
        float qa = 0.f;
#pragma unroll
        for (int l = 0; l < Cc; ++l) qa += sQ[(i * Cc + l) * Gg + g] * al[l];
        float v = smB1[(i * Mm + xv) * Gg + g] * qa;
        t[i] = v;
        norm += v;
    }
    float inv = 1.0f / norm;
#pragma unroll
    for (int i = 0; i < Cc; ++i)
        stout(out, (size_t)Nn * 2 * Gg + (size_t)n * (Cc * Gg) + i * Gg + g, t[i] * inv, isbf);
    stout(out, (size_t)n * (2 * Gg) + Gg + g, logf(norm), isbf);
}

// ---------------------------------------------------------------------------
extern "C" void kernel_launch(void* const* d_in, const int* in_sizes, int n_in,
                              void* d_out, int out_size, void* d_ws, size_t ws_size,
                              hipStream_t stream) {
    const int* x  = (const int*)d_in[0];
    const int* ei = (const int*)d_in[1];
    const void* B0 = d_in[2];
    const void* Pi = d_in[3];
    const void* B1 = d_in[4];
    const void* Q  = d_in[5];

    // Workspace layout (fp32 words):
    float* ws    = (float*)d_ws;
    int*   flag  = (int*)ws;                       // 1 (padded to 128)
    float* smPi  = ws + 128;                       // 128
    float* smB0  = smPi + 128;                     // 4096
    float* smB1  = smB0 + 4096;                    // 4096
    float* smQ   = smB1 + 4096;                    // 2048
    float* aggr  = smQ + 2048;                     // 6,400,000 fp32 (16B-aligned)
    __hip_bfloat16* post0 = (__hip_bfloat16*)(aggr + (size_t)Nn * Cc * Gg);  // 6.4M bf16
    int*   deg        = (int*)((unsigned short*)post0 + (size_t)Nn * Cc * Gg); // 50,000
    int*   offs       = deg + Nn;                  // 50,000
    int*   cursor     = offs + Nn;                 // 50,000
    int*   bsum       = cursor + Nn;               // 256
    int*   boff       = bsum + 256;                // 256
    int*   sorted_dst = boff + 256;                // 800,000
    // total ~42 MB

    hipMemsetAsync(deg, 0, Nn * sizeof(int), stream);

    detect_and_tables<<<1, 256, 0, stream>>>(B0, Pi, B1, Q, flag, smB0, smPi, smB1, smQ);

    count_kernel<<<(Ee + 255) / 256, 256, 0, stream>>>(ei, deg);
    scanA<<<SCAN_BLOCKS, SCAN_T, 0, stream>>>(deg, bsum);
    scanB<<<1, SCAN_T, 0, stream>>>(bsum, boff);
    scanC<<<SCAN_BLOCKS, SCAN_T, 0, stream>>>(deg, boff, offs, cursor);
    fill_kernel<<<(Ee + 255) / 256, 256, 0, stream>>>(ei, cursor, sorted_dst);

    int ng = Nn * Gg;  // 400,000
    layer0_kernel<<<(ng + 255) / 256, 256, 0, stream>>>(x, smPi, smB0, flag, post0, d_out);

    long long at = (long long)Nn * 64;   // one wave per node
    aggr_kernel<<<(int)((at + 255) / 256), 256, 0, stream>>>(
        offs, deg, sorted_dst, (const unsigned short*)post0, aggr);

    layer1_kernel<<<(ng + 255) / 256, 256, 0, stream>>>(x, smB1, smQ, aggr, flag, d_out);
}

// Round 5
// 218.468 us; speedup vs baseline: 6.8477x; 1.2148x over previous
//
#include <hip/hip_runtime.h>
#include <hip/hip_bf16.h>
#include <math.h>

#define Nn 50000
#define Ee 800000
#define Cc 16
#define Mm 32
#define Gg 8

#define SCAN_T 256
#define SCAN_BLOCKS ((Nn + SCAN_T - 1) / SCAN_T)   // 196

#define FILLB 1024                                  // fill blocks (128 per XCD group)
#define L0B ((Nn * Gg + 255) / 256)                 // 1563 layer0 blocks
#define NPG (Nn / 8)                                // 6250 src nodes per XCD group

// ---------------------------------------------------------------------------
// dtype-agnostic load/store helpers. isbf is wave-uniform -> scalar branch.
// ---------------------------------------------------------------------------
__device__ __forceinline__ float ldin(const void* p, int idx, int isbf) {
    if (isbf) return __bfloat162float(((const __hip_bfloat16*)p)[idx]);
    return ((const float*)p)[idx];
}
__device__ __forceinline__ void stout(void* p, size_t idx, float v, int isbf) {
    if (isbf) ((__hip_bfloat16*)p)[idx] = __float2bfloat16(v);
    else ((float*)p)[idx] = v;
}

// ---------------------------------------------------------------------------
// Kernel 1: block 0 = dtype detect + softmax tables; blocks >=1 = degree count
// ---------------------------------------------------------------------------
__global__ void tables_count(const void* __restrict__ B0,
                             const void* __restrict__ Pi,
                             const void* __restrict__ B1,
                             const void* __restrict__ Q,
                             const int* __restrict__ ei,
                             int* __restrict__ flag_ws,
                             float* __restrict__ smB0,
                             float* __restrict__ smPi,
                             float* __restrict__ smB1,
                             float* __restrict__ smQ,
                             int* __restrict__ deg) {
    if (blockIdx.x > 0) {   // ---- count ----
        int e = (blockIdx.x - 1) * blockDim.x + threadIdx.x;
        if (e < Ee) atomicAdd(&deg[ei[e]], 1);
        return;
    }
    // ---- block 0: detect + tables ----
    __shared__ int sflag;
    if (threadIdx.x == 0) {
        const unsigned int* w = (const unsigned int*)B0;
        int cnt = 0;
        for (int k = 0; k < 64; ++k) {
            unsigned int ex = (w[k] >> 7) & 0xFFu;
            if (ex >= 120u && ex <= 130u) cnt++;
        }
        sflag = (cnt >= 48) ? 1 : 0;
        *flag_ws = sflag;
    }
    __syncthreads();
    const int isbf = sflag;
    int tid = threadIdx.x;

    if (tid < 128) {
        int c = tid / Gg, g = tid % Gg;
        int base = c * (Mm * Gg) + g;
        float mx = -1e30f;
        for (int m = 0; m < Mm; ++m) mx = fmaxf(mx, ldin(B0, base + m * Gg, isbf));
        float s = 0.f;
        for (int m = 0; m < Mm; ++m) s += __expf(ldin(B0, base + m * Gg, isbf) - mx);
        float inv = 1.0f / s;
        for (int m = 0; m < Mm; ++m)
            smB0[base + m * Gg] = __expf(ldin(B0, base + m * Gg, isbf) - mx) * inv;
    } else {
        int t = tid - 128;
        int c = t / Gg, g = t % Gg;
        int base = c * (Mm * Gg) + g;
        float mx = -1e30f;
        for (int m = 0; m < Mm; ++m) mx = fmaxf(mx, ldin(B1, base + m * Gg, isbf));
        float s = 0.f;
        for (int m = 0; m < Mm; ++m) s += __expf(ldin(B1, base + m * Gg, isbf) - mx);
        float inv = 1.0f / s;
        for (int m = 0; m < Mm; ++m)
            smB1[base + m * Gg] = __expf(ldin(B1, base + m * Gg, isbf) - mx) * inv;
    }

    if (tid < 128) {   // Q[i,l,g]: softmax over i
        int l = tid / Gg, g = tid % Gg;
        int base = l * Gg + g;
        float mx = -1e30f;
        for (int i = 0; i < Cc; ++i) mx = fmaxf(mx, ldin(Q, base + i * Cc * Gg, isbf));
        float s = 0.f;
        for (int i = 0; i < Cc; ++i) s += __expf(ldin(Q, base + i * Cc * Gg, isbf) - mx);
        float inv = 1.0f / s;
        for (int i = 0; i < Cc; ++i)
            smQ[base + i * Cc * Gg] = __expf(ldin(Q, base + i * Cc * Gg, isbf) - mx) * inv;
    }

    if (tid < Gg) {    // Pi[c,g]: softmax over c
        int g = tid;
        float mx = -1e30f;
        for (int c = 0; c < Cc; ++c) mx = fmaxf(mx, ldin(Pi, c * Gg + g, isbf));
        float s = 0.f;
        for (int c = 0; c < Cc; ++c) s += __expf(ldin(Pi, c * Gg + g, isbf) - mx);
        float inv = 1.0f / s;
        for (int c = 0; c < Cc; ++c)
            smPi[c * Gg + g] = __expf(ldin(Pi, c * Gg + g, isbf) - mx) * inv;
    }
}

// ---------------------------------------------------------------------------
// Multi-block exclusive scan over deg (3 phases)
// ---------------------------------------------------------------------------
__global__ void scanA(const int* __restrict__ deg, int* __restrict__ bsum) {
    __shared__ int s[SCAN_T];
    int i = blockIdx.x * SCAN_T + threadIdx.x;
    s[threadIdx.x] = (i < Nn) ? deg[i] : 0;
    __syncthreads();
    for (int off = SCAN_T / 2; off > 0; off >>= 1) {
        if (threadIdx.x < off) s[threadIdx.x] += s[threadIdx.x + off];
        __syncthreads();
    }
    if (threadIdx.x == 0) bsum[blockIdx.x] = s[0];
}

__global__ void scanB(const int* __restrict__ bsum, int* __restrict__ boff) {
    __shared__ int s[SCAN_T];
    int t = threadIdx.x;
    int v = (t < SCAN_BLOCKS) ? bsum[t] : 0;
    s[t] = v;
    __syncthreads();
    for (int off = 1; off < SCAN_T; off <<= 1) {
        int u = (t >= off) ? s[t - off] : 0;
        __syncthreads();
        s[t] += u;
        __syncthreads();
    }
    if (t < SCAN_BLOCKS) boff[t] = s[t] - v;   // exclusive
}

__global__ void scanC(const int* __restrict__ deg, const int* __restrict__ boff,
                      int* __restrict__ offs, int* __restrict__ cursor) {
    __shared__ int s[SCAN_T];
    int t = threadIdx.x;
    int i = blockIdx.x * SCAN_T + t;
    int v = (i < Nn) ? deg[i] : 0;
    s[t] = v;
    __syncthreads();
    for (int off = 1; off < SCAN_T; off <<= 1) {
        int u = (t >= off) ? s[t - off] : 0;
        __syncthreads();
        s[t] += u;
        __syncthreads();
    }
    int ex = s[t] - v + boff[blockIdx.x];
    if (i < Nn) { offs[i] = ex; cursor[i] = ex; }
}

// ---------------------------------------------------------------------------
// Kernel 2: fused fill (XCD-bucketed) + layer0
//   Blocks [0,FILLB): group = blockIdx%8 (round-robin -> same XCD); each group
//   strides the full edge list, committing only src in its contiguous range ->
//   sorted_dst writes land in one contiguous ~400KB region per XCD's L2.
//   Blocks [FILLB, FILLB+L0B): layer0, thread per (n,g), post0 stored bf16.
// ---------------------------------------------------------------------------
__global__ void fill_layer0(const int* __restrict__ ei,
                            int* __restrict__ cursor,
                            int* __restrict__ sorted_dst,
                            const int* __restrict__ x,
                            const float* __restrict__ smPi,
                            const float* __restrict__ smB0,
                            const int* __restrict__ flag_ws,
                            __hip_bfloat16* __restrict__ post0,
                            void* __restrict__ out) {
    int b = blockIdx.x;
    if (b < FILLB) {
        int grp = b & 7;
        int sub = b >> 3;                       // 0..127
        int lo = grp * NPG, hi = lo + NPG;
        const int stride = (FILLB >> 3) * 256;  // 32768
        for (int e = sub * 256 + threadIdx.x; e < Ee; e += stride) {
            int s = ei[e];
            if (s >= lo && s < hi) {
                int d = ei[Ee + e];
                int pos = atomicAdd(&cursor[s], 1);
                sorted_dst[pos] = d;
            }
        }
        return;
    }
    // ---- layer0 ----
    int tid = (b - FILLB) * 256 + threadIdx.x;
    if (tid >= Nn * Gg) return;
    const int isbf = *flag_ws;
    int n = tid / Gg, g = tid % Gg;
    int xv = x[n];
    float u[Cc];
    float norm = 0.f;
#pragma unroll
    for (int c = 0; c < Cc; ++c) {
        float v = smPi[c * Gg + g] * smB0[(c * Mm + xv) * Gg + g];
        u[c] = v;
        norm += v;
    }
    float inv = 1.0f / norm;
#pragma unroll
    for (int c = 0; c < Cc; ++c)
        post0[n * (Cc * Gg) + c * Gg + g] = __float2bfloat16(u[c] * inv);
    stout(out, (size_t)n * (2 * Gg) + g, logf(norm), isbf);
}

// ---------------------------------------------------------------------------
// Kernel 3: aggregation — one wave per node, quarter-wave per edge row.
//   16 lanes x uint4 (8 bf16 = 16B) cover a 256B row; 4 edges in flight/iter.
//   fp32 accumulate, shfl_xor(16)+shfl_xor(32) combine, mean applied here.
// ---------------------------------------------------------------------------
__global__ void aggr_kernel(const int* __restrict__ offs,
                            const int* __restrict__ deg,
                            const int* __restrict__ sorted_dst,
                            const unsigned short* __restrict__ post0,
                            float* __restrict__ aggr) {
    int wave = (int)((blockIdx.x * (long long)blockDim.x + threadIdx.x) >> 6);
    if (wave >= Nn) return;
    int lane = threadIdx.x & 63;
    int q = lane >> 4, j = lane & 15;           // quarter, lane-in-quarter
    int start = offs[wave];
    int d = deg[wave];
    int end = start + d;
    float a[8];
#pragma unroll
    for (int k = 0; k < 8; ++k) a[k] = 0.f;
    for (int e = start + q; e < end; e += 4) {
        int dst = sorted_dst[e];
        const uint4 v = *(const uint4*)(post0 + (size_t)dst * 128 + j * 8);
        a[0] += __uint_as_float(v.x << 16);
        a[1] += __uint_as_float(v.x & 0xffff0000u);
        a[2] += __uint_as_float(v.y << 16);
        a[3] += __uint_as_float(v.y & 0xffff0000u);
        a[4] += __uint_as_float(v.z << 16);
        a[5] += __uint_as_float(v.z & 0xffff0000u);
        a[6] += __uint_as_float(v.w << 16);
        a[7] += __uint_as_float(v.w & 0xffff0000u);
    }
#pragma unroll
    for (int k = 0; k < 8; ++k) {
        a[k] += __shfl_xor(a[k], 16, 64);
        a[k] += __shfl_xor(a[k], 32, 64);
    }
    if (q == 0) {
        float inv = 1.0f / fmaxf((float)d, 1.0f);
        float4 r0 = {a[0] * inv, a[1] * inv, a[2] * inv, a[3] * inv};
        float4 r1 = {a[4] * inv, a[5] * inv, a[6] * inv, a[7] * inv};
        float* base = aggr + (size_t)wave * 128 + j * 8;
        *(float4*)(base) = r0;
        *(float4*)(base + 4) = r1;
    }
}

// ---------------------------------------------------------------------------
// Kernel 4: layer 1 — one thread per (n, g); smQ staged in LDS (8 KB)
// ---------------------------------------------------------------------------
__global__ void layer1_kernel(const int* __restrict__ x,
                              const float* __restrict__ smB1,
                              const float* __restrict__ smQ,
                              const float* __restrict__ aggr,
                              const int* __restrict__ flag_ws,
                              void* __restrict__ out) {
    __shared__ float sQ[Cc * Cc * Gg];
    for (int i = threadIdx.x; i < Cc * Cc * Gg; i += blockDim.x) sQ[i] = smQ[i];
    __syncthreads();

    int tid = blockIdx.x * blockDim.x + threadIdx.x;
    if (tid >= Nn * Gg) return;
    const int isbf = *flag_ws;
    int n = tid / Gg, g = tid % Gg;

    float al[Cc];
#pragma unroll
    for (int l = 0; l < Cc; ++l) al[l] = aggr[(size_t)n * 128 + l * Gg + g];

    int xv = x[n];
    float t[Cc];
    float norm = 0.f;
#pragma unroll
    for (int i = 0; i < Cc; ++i) {
        float qa = 0.f;
#pragma unroll
        for (int l = 0; l < Cc; ++l) qa += sQ[(i * Cc + l) * Gg + g] * al[l];
        float v = smB1[(i * Mm + xv) * Gg + g] * qa;
        t[i] = v;
        norm += v;
    }
    float inv = 1.0f / norm;
#pragma unroll
    for (int i = 0; i < Cc; ++i)
        stout(out, (size_t)Nn * 2 * Gg + (size_t)n * (Cc * Gg) + i * Gg + g, t[i] * inv, isbf);
    stout(out, (size_t)n * (2 * Gg) + Gg + g, logf(norm), isbf);
}

// ---------------------------------------------------------------------------
extern "C" void kernel_launch(void* const* d_in, const int* in_sizes, int n_in,
                              void* d_out, int out_size, void* d_ws, size_t ws_size,
                              hipStream_t stream) {
    const int* x  = (const int*)d_in[0];
    const int* ei = (const int*)d_in[1];
    const void* B0 = d_in[2];
    const void* Pi = d_in[3];
    const void* B1 = d_in[4];
    const void* Q  = d_in[5];

    // Workspace layout (fp32 words):
    float* ws    = (float*)d_ws;
    int*   flag  = (int*)ws;                       // 1 (padded to 128)
    float* smPi  = ws + 128;                       // 128
    float* smB0  = smPi + 128;                     // 4096
    float* smB1  = smB0 + 4096;                    // 4096
    float* smQ   = smB1 + 4096;                    // 2048
    float* aggr  = smQ + 2048;                     // 6,400,000 fp32 (16B-aligned)
    __hip_bfloat16* post0 = (__hip_bfloat16*)(aggr + (size_t)Nn * Cc * Gg);  // 6.4M bf16
    int*   deg        = (int*)((unsigned short*)post0 + (size_t)Nn * Cc * Gg); // 50,000
    int*   offs       = deg + Nn;                  // 50,000
    int*   cursor     = offs + Nn;                 // 50,000
    int*   bsum       = cursor + Nn;               // 256
    int*   boff       = bsum + 256;                // 256
    int*   sorted_dst = boff + 256;                // 800,000
    // total ~42 MB

    hipMemsetAsync(deg, 0, Nn * sizeof(int), stream);

    tables_count<<<1 + (Ee + 255) / 256, 256, 0, stream>>>(
        B0, Pi, B1, Q, ei, flag, smB0, smPi, smB1, smQ, deg);

    scanA<<<SCAN_BLOCKS, SCAN_T, 0, stream>>>(deg, bsum);
    scanB<<<1, SCAN_T, 0, stream>>>(bsum, boff);
    scanC<<<SCAN_BLOCKS, SCAN_T, 0, stream>>>(deg, boff, offs, cursor);

    fill_layer0<<<FILLB + L0B, 256, 0, stream>>>(
        ei, cursor, sorted_dst, x, smPi, smB0, flag, post0, d_out);

    long long at = (long long)Nn * 64;   // one wave per node
    aggr_kernel<<<(int)((at + 255) / 256), 256, 0, stream>>>(
        offs, deg, sorted_dst, (const unsigned short*)post0, aggr);

    layer1_kernel<<<(Nn * Gg + 255) / 256, 256, 0, stream>>>(
        x, smB1, smQ, aggr, flag, d_out);
}

// Round 6
// 209.934 us; speedup vs baseline: 7.1261x; 1.0406x over previous
//
#include <hip/hip_runtime.h>
#include <hip/hip_bf16.h>
#include <math.h>

#define Nn 50000
#define Ee 800000
#define Cc 16
#define Mm 32
#define Gg 8

#define SCAN_T 256
#define SCAN_BLOCKS ((Nn + SCAN_T - 1) / SCAN_T)   // 196

#define FILLB 1024                                  // fill blocks (128 per XCD group)
#define L0B ((Nn * Gg + 255) / 256)                 // layer0 blocks
#define COUNTB 1024                                 // count blocks (128 per XCD group)
#define NPG (Nn / 8)                                // 6250 src nodes per XCD group

// ---------------------------------------------------------------------------
// dtype-agnostic load/store helpers. isbf is wave-uniform -> scalar branch.
// ---------------------------------------------------------------------------
__device__ __forceinline__ float ldin(const void* p, int idx, int isbf) {
    if (isbf) return __bfloat162float(((const __hip_bfloat16*)p)[idx]);
    return ((const float*)p)[idx];
}
__device__ __forceinline__ void stout(void* p, size_t idx, float v, int isbf) {
    if (isbf) ((__hip_bfloat16*)p)[idx] = __float2bfloat16(v);
    else ((float*)p)[idx] = v;
}

// ---------------------------------------------------------------------------
// Kernel 1: block 0 = dtype detect + LDS-staged softmax tables;
//           blocks >=1 = XCD-bucketed degree count (deg lines stay in one L2)
// ---------------------------------------------------------------------------
__global__ void tables_count(const void* __restrict__ B0,
                             const void* __restrict__ Pi,
                             const void* __restrict__ B1,
                             const void* __restrict__ Q,
                             const int* __restrict__ ei,
                             int* __restrict__ flag_ws,
                             float* __restrict__ smB0,
                             float* __restrict__ smPi,
                             float* __restrict__ smB1,
                             float* __restrict__ smQ,
                             int* __restrict__ deg) {
    if (blockIdx.x > 0) {   // ---- bucketed count ----
        int b = blockIdx.x - 1;
        int grp = b & 7;
        int sub = b >> 3;                        // 0..127
        int lo = grp * NPG, hi = lo + NPG;
        const int stride = (COUNTB >> 3) * 256;  // 32768
        for (int e = sub * 256 + threadIdx.x; e < Ee; e += stride) {
            int s = ei[e];
            if (s >= lo && s < hi) atomicAdd(&deg[s], 1);
        }
        return;
    }
    // ---- block 0: detect + tables from LDS ----
    __shared__ float sB0[Cc * Mm * Gg];   // 4096
    __shared__ float sB1[Cc * Mm * Gg];   // 4096
    __shared__ float sQl[Cc * Cc * Gg];   // 2048
    __shared__ float sPi[Cc * Gg];        // 128
    __shared__ int sflag;
    int tid = threadIdx.x;

    if (tid < 64) {   // wave-parallel dtype detect on wave 0
        unsigned int wv = ((const unsigned int*)B0)[tid];
        unsigned int ex = (wv >> 7) & 0xFFu;
        unsigned long long m = __ballot(ex >= 120u && ex <= 130u);
        if (tid == 0) {
            sflag = (__popcll(m) >= 48) ? 1 : 0;
            *flag_ws = sflag;
        }
    }
    __syncthreads();
    const int isbf = sflag;

    for (int i = tid; i < Cc * Mm * Gg; i += 256) sB0[i] = ldin(B0, i, isbf);
    for (int i = tid; i < Cc * Mm * Gg; i += 256) sB1[i] = ldin(B1, i, isbf);
    for (int i = tid; i < Cc * Cc * Gg; i += 256) sQl[i] = ldin(Q, i, isbf);
    if (tid < Cc * Gg) sPi[tid] = ldin(Pi, tid, isbf);
    __syncthreads();

    if (tid < 128) {              // B0 col (c,g): softmax over m, stride G
        int base = (tid / Gg) * (Mm * Gg) + (tid % Gg);
        float mx = -1e30f;
        for (int m = 0; m < Mm; ++m) mx = fmaxf(mx, sB0[base + m * Gg]);
        float s = 0.f;
        for (int m = 0; m < Mm; ++m) s += __expf(sB0[base + m * Gg] - mx);
        float inv = 1.0f / s;
        for (int m = 0; m < Mm; ++m)
            smB0[base + m * Gg] = __expf(sB0[base + m * Gg] - mx) * inv;
    } else {                      // B1 col
        int t = tid - 128;
        int base = (t / Gg) * (Mm * Gg) + (t % Gg);
        float mx = -1e30f;
        for (int m = 0; m < Mm; ++m) mx = fmaxf(mx, sB1[base + m * Gg]);
        float s = 0.f;
        for (int m = 0; m < Mm; ++m) s += __expf(sB1[base + m * Gg] - mx);
        float inv = 1.0f / s;
        for (int m = 0; m < Mm; ++m)
            smB1[base + m * Gg] = __expf(sB1[base + m * Gg] - mx) * inv;
    }

    if (tid < 128) {              // Q col (l,g): softmax over i, stride C*G
        int base = (tid / Gg) * Gg + (tid % Gg);
        float mx = -1e30f;
        for (int i = 0; i < Cc; ++i) mx = fmaxf(mx, sQl[base + i * Cc * Gg]);
        float s = 0.f;
        for (int i = 0; i < Cc; ++i) s += __expf(sQl[base + i * Cc * Gg] - mx);
        float inv = 1.0f / s;
        for (int i = 0; i < Cc; ++i)
            smQ[base + i * Cc * Gg] = __expf(sQl[base + i * Cc * Gg] - mx) * inv;
    }

    if (tid < Gg) {               // Pi col g: softmax over c, stride G
        int g = tid;
        float mx = -1e30f;
        for (int c = 0; c < Cc; ++c) mx = fmaxf(mx, sPi[c * Gg + g]);
        float s = 0.f;
        for (int c = 0; c < Cc; ++c) s += __expf(sPi[c * Gg + g] - mx);
        float inv = 1.0f / s;
        for (int c = 0; c < Cc; ++c)
            smPi[c * Gg + g] = __expf(sPi[c * Gg + g] - mx) * inv;
    }
}

// ---------------------------------------------------------------------------
// Multi-block exclusive scan over deg: scanA (block sums) + scanC (fused
// block-offset scan + per-block scan)
// ---------------------------------------------------------------------------
__global__ void scanA(const int* __restrict__ deg, int* __restrict__ bsum) {
    __shared__ int s[SCAN_T];
    int i = blockIdx.x * SCAN_T + threadIdx.x;
    s[threadIdx.x] = (i < Nn) ? deg[i] : 0;
    __syncthreads();
    for (int off = SCAN_T / 2; off > 0; off >>= 1) {
        if (threadIdx.x < off) s[threadIdx.x] += s[threadIdx.x + off];
        __syncthreads();
    }
    if (threadIdx.x == 0) bsum[blockIdx.x] = s[0];
}

__global__ void scanC(const int* __restrict__ deg, const int* __restrict__ bsum,
                      int* __restrict__ offs, int* __restrict__ cursor) {
    __shared__ int sb[SCAN_T];
    __shared__ int s[SCAN_T];
    int t = threadIdx.x;
    // scan the 196 block sums (redundant per block, cheap)
    int bv = (t < SCAN_BLOCKS) ? bsum[t] : 0;
    sb[t] = bv;
    __syncthreads();
    for (int off = 1; off < SCAN_T; off <<= 1) {
        int u = (t >= off) ? sb[t - off] : 0;
        __syncthreads();
        sb[t] += u;
        __syncthreads();
    }
    int i = blockIdx.x * SCAN_T + t;
    int v = (i < Nn) ? deg[i] : 0;
    s[t] = v;
    __syncthreads();
    for (int off = 1; off < SCAN_T; off <<= 1) {
        int u = (t >= off) ? s[t - off] : 0;
        __syncthreads();
        s[t] += u;
        __syncthreads();
    }
    int boff = sb[blockIdx.x] - bsum[blockIdx.x];   // exclusive block offset
    int ex = s[t] - v + boff;
    if (i < Nn) { offs[i] = ex; cursor[i] = ex; }
}

// ---------------------------------------------------------------------------
// Kernel 2: fused fill (XCD-bucketed) + layer0
// ---------------------------------------------------------------------------
__global__ void fill_layer0(const int* __restrict__ ei,
                            int* __restrict__ cursor,
                            int* __restrict__ sorted_dst,
                            const int* __restrict__ x,
                            const float* __restrict__ smPi,
                            const float* __restrict__ smB0,
                            const int* __restrict__ flag_ws,
                            __hip_bfloat16* __restrict__ post0,
                            void* __restrict__ out) {
    int b = blockIdx.x;
    if (b < FILLB) {
        int grp = b & 7;
        int sub = b >> 3;                       // 0..127
        int lo = grp * NPG, hi = lo + NPG;
        const int stride = (FILLB >> 3) * 256;  // 32768
        for (int e = sub * 256 + threadIdx.x; e < Ee; e += stride) {
            int s = ei[e];
            if (s >= lo && s < hi) {
                int d = ei[Ee + e];
                int pos = atomicAdd(&cursor[s], 1);
                sorted_dst[pos] = d;
            }
        }
        return;
    }
    // ---- layer0 ----
    int tid = (b - FILLB) * 256 + threadIdx.x;
    if (tid >= Nn * Gg) return;
    const int isbf = *flag_ws;
    int n = tid / Gg, g = tid % Gg;
    int xv = x[n];
    float u[Cc];
    float norm = 0.f;
#pragma unroll
    for (int c = 0; c < Cc; ++c) {
        float v = smPi[c * Gg + g] * smB0[(c * Mm + xv) * Gg + g];
        u[c] = v;
        norm += v;
    }
    float inv = 1.0f / norm;
#pragma unroll
    for (int c = 0; c < Cc; ++c)
        post0[n * (Cc * Gg) + c * Gg + g] = __float2bfloat16(u[c] * inv);
    stout(out, (size_t)n * (2 * Gg) + g, logf(norm), isbf);
}

// ---------------------------------------------------------------------------
// Kernel 3: aggregation — one wave per node, quarter-wave per edge row.
// ---------------------------------------------------------------------------
__global__ void aggr_kernel(const int* __restrict__ offs,
                            const int* __restrict__ deg,
                            const int* __restrict__ sorted_dst,
                            const unsigned short* __restrict__ post0,
                            float* __restrict__ aggr) {
    int wave = (int)((blockIdx.x * (long long)blockDim.x + threadIdx.x) >> 6);
    if (wave >= Nn) return;
    int lane = threadIdx.x & 63;
    int q = lane >> 4, j = lane & 15;           // quarter, lane-in-quarter
    int start = offs[wave];
    int d = deg[wave];
    int end = start + d;
    float a[8];
#pragma unroll
    for (int k = 0; k < 8; ++k) a[k] = 0.f;
    for (int e = start + q; e < end; e += 4) {
        int dst = sorted_dst[e];
        const uint4 v = *(const uint4*)(post0 + (size_t)dst * 128 + j * 8);
        a[0] += __uint_as_float(v.x << 16);
        a[1] += __uint_as_float(v.x & 0xffff0000u);
        a[2] += __uint_as_float(v.y << 16);
        a[3] += __uint_as_float(v.y & 0xffff0000u);
        a[4] += __uint_as_float(v.z << 16);
        a[5] += __uint_as_float(v.z & 0xffff0000u);
        a[6] += __uint_as_float(v.w << 16);
        a[7] += __uint_as_float(v.w & 0xffff0000u);
    }
#pragma unroll
    for (int k = 0; k < 8; ++k) {
        a[k] += __shfl_xor(a[k], 16, 64);
        a[k] += __shfl_xor(a[k], 32, 64);
    }
    if (q == 0) {
        float inv = 1.0f / fmaxf((float)d, 1.0f);
        float4 r0 = {a[0] * inv, a[1] * inv, a[2] * inv, a[3] * inv};
        float4 r1 = {a[4] * inv, a[5] * inv, a[6] * inv, a[7] * inv};
        float* base = aggr + (size_t)wave * 128 + j * 8;
        *(float4*)(base) = r0;
        *(float4*)(base + 4) = r1;
    }
}

// ---------------------------------------------------------------------------
// Kernel 4: layer 1 — one thread per (n, g); smQ staged in LDS (8 KB)
// ---------------------------------------------------------------------------
__global__ void layer1_kernel(const int* __restrict__ x,
                              const float* __restrict__ smB1,
                              const float* __restrict__ smQ,
                              const float* __restrict__ aggr,
                              const int* __restrict__ flag_ws,
                              void* __restrict__ out) {
    __shared__ float sQ[Cc * Cc * Gg];
    for (int i = threadIdx.x; i < Cc * Cc * Gg; i += blockDim.x) sQ[i] = smQ[i];
    __syncthreads();

    int tid = blockIdx.x * blockDim.x + threadIdx.x;
    if (tid >= Nn * Gg) return;
    const int isbf = *flag_ws;
    int n = tid / Gg, g = tid % Gg;

    float al[Cc];
#pragma unroll
    for (int l = 0; l < Cc; ++l) al[l] = aggr[(size_t)n * 128 + l * Gg + g];

    int xv = x[n];
    float t[Cc];
    float norm = 0.f;
#pragma unroll
    for (int i = 0; i < Cc; ++i) {
        float qa = 0.f;
#pragma unroll
        for (int l = 0; l < Cc; ++l) qa += sQ[(i * Cc + l) * Gg + g] * al[l];
        float v = smB1[(i * Mm + xv) * Gg + g] * qa;
        t[i] = v;
        norm += v;
    }
    float inv = 1.0f / norm;
#pragma unroll
    for (int i = 0; i < Cc; ++i)
        stout(out, (size_t)Nn * 2 * Gg + (size_t)n * (Cc * Gg) + i * Gg + g, t[i] * inv, isbf);
    stout(out, (size_t)n * (2 * Gg) + Gg + g, logf(norm), isbf);
}

// ---------------------------------------------------------------------------
extern "C" void kernel_launch(void* const* d_in, const int* in_sizes, int n_in,
                              void* d_out, int out_size, void* d_ws, size_t ws_size,
                              hipStream_t stream) {
    const int* x  = (const int*)d_in[0];
    const int* ei = (const int*)d_in[1];
    const void* B0 = d_in[2];
    const void* Pi = d_in[3];
    const void* B1 = d_in[4];
    const void* Q  = d_in[5];

    // Workspace layout (fp32 words):
    float* ws    = (float*)d_ws;
    int*   flag  = (int*)ws;                       // 1 (padded to 128)
    float* smPi  = ws + 128;                       // 128
    float* smB0  = smPi + 128;                     // 4096
    float* smB1  = smB0 + 4096;                    // 4096
    float* smQ   = smB1 + 4096;                    // 2048
    float* aggr  = smQ + 2048;                     // 6,400,000 fp32 (16B-aligned)
    __hip_bfloat16* post0 = (__hip_bfloat16*)(aggr + (size_t)Nn * Cc * Gg);  // 6.4M bf16
    int*   deg        = (int*)((unsigned short*)post0 + (size_t)Nn * Cc * Gg); // 50,000
    int*   offs       = deg + Nn;                  // 50,000
    int*   cursor     = offs + Nn;                 // 50,000
    int*   bsum       = cursor + Nn;               // 256
    int*   sorted_dst = bsum + 256;                // 800,000
    // total ~42 MB

    hipMemsetAsync(deg, 0, Nn * sizeof(int), stream);

    tables_count<<<1 + COUNTB, 256, 0, stream>>>(
        B0, Pi, B1, Q, ei, flag, smB0, smPi, smB1, smQ, deg);

    scanA<<<SCAN_BLOCKS, SCAN_T, 0, stream>>>(deg, bsum);
    scanC<<<SCAN_BLOCKS, SCAN_T, 0, stream>>>(deg, bsum, offs, cursor);

    fill_layer0<<<FILLB + L0B, 256, 0, stream>>>(
        ei, cursor, sorted_dst, x, smPi, smB0, flag, post0, d_out);

    long long at = (long long)Nn * 64;   // one wave per node
    aggr_kernel<<<(int)((at + 255) / 256), 256, 0, stream>>>(
        offs, deg, sorted_dst, (const unsigned short*)post0, aggr);

    layer1_kernel<<<(Nn * Gg + 255) / 256, 256, 0, stream>>>(
        x, smB1, smQ, aggr, flag, d_out);
}